// Round 1
// baseline (5805.047 us; speedup 1.0000x reference)
//
#include <hip/hip_runtime.h>
#include <cstdint>

static constexpr int N_NODES = 300000;
static constexpr int N_NETS  = 200000;
static constexpr int E_SINK  = 1000000;
static constexpr int NODE_DIM = 32;
static constexpr int NET_DIM  = 16;
static constexpr int EMB = 64;
static constexpr int NUM_VN = 1000;
#define SLOPE 0.01f

__device__ __forceinline__ float leaky(float x) { return x >= 0.f ? x : SLOPE * x; }

// order-preserving f32 -> u32 encoding for atomicMax
__device__ __forceinline__ unsigned enc(float x) {
    unsigned u = __float_as_uint(x);
    return (u & 0x80000000u) ? ~u : (u | 0x80000000u);
}
__device__ __forceinline__ float dec(unsigned e) {
    unsigned u = (e & 0x80000000u) ? (e ^ 0x80000000u) : ~e;
    return __uint_as_float(u);
}

// ---------------- encoders ----------------
__global__ __launch_bounds__(256) void k_node_enc(
    const float* __restrict__ x, const float* __restrict__ W1, const float* __restrict__ b1,
    const float* __restrict__ W2, const float* __restrict__ b2, float* __restrict__ h)
{
    int wv = threadIdx.x >> 6, lane = threadIdx.x & 63;
    int node = blockIdx.x * 4 + wv;
    if (node >= N_NODES) return;
    const float* xr = x + node * NODE_DIM;
    float h0 = b1[lane], h1 = b1[lane + 64];
#pragma unroll
    for (int i = 0; i < NODE_DIM; ++i) {
        float xi = xr[i];
        h0 += xi * W1[i * 128 + lane];
        h1 += xi * W1[i * 128 + 64 + lane];
    }
    h0 = leaky(h0); h1 = leaky(h1);
    float acc = b2[lane];
#pragma unroll 16
    for (int k = 0; k < 64; ++k) acc += __shfl(h0, k, 64) * W2[k * 64 + lane];
#pragma unroll 16
    for (int k = 0; k < 64; ++k) acc += __shfl(h1, k, 64) * W2[(64 + k) * 64 + lane];
    h[node * 64 + lane] = acc;
}

__global__ __launch_bounds__(256) void k_net_enc(
    const float* __restrict__ x, const float* __restrict__ W1, const float* __restrict__ b1,
    const float* __restrict__ W2, const float* __restrict__ b2, float* __restrict__ g)
{
    int wv = threadIdx.x >> 6, lane = threadIdx.x & 63;
    int net = blockIdx.x * 4 + wv;
    if (net >= N_NETS) return;
    const float* xr = x + net * NET_DIM;
    float hd = b1[lane];
#pragma unroll
    for (int i = 0; i < NET_DIM; ++i) hd += xr[i] * W1[i * 64 + lane];
    hd = leaky(hd);
    float acc = b2[lane];
#pragma unroll 16
    for (int k = 0; k < 64; ++k) acc += __shfl(hd, k, 64) * W2[k * 64 + lane];
    g[net * 64 + lane] = acc;
}

// ---------------- misc elementwise ----------------
__global__ void k_vn_init(float* __restrict__ vn, const float* __restrict__ vn_emb) {
    int idx = blockIdx.x * blockDim.x + threadIdx.x;
    if (idx < NUM_VN * EMB) vn[idx] = vn_emb[idx & 63];
}

__global__ void k_add_vn(float* __restrict__ h, const float* __restrict__ vn,
                         const int* __restrict__ batch) {
    int idx = blockIdx.x * blockDim.x + threadIdx.x;
    if (idx >= N_NODES * EMB) return;
    int n = idx >> 6, c = idx & 63;
    h[idx] += vn[batch[n] * 64 + c];
}

__global__ void k_pool_init(unsigned* __restrict__ pooled) {
    int idx = blockIdx.x * blockDim.x + threadIdx.x;
    if (idx < NUM_VN * EMB) pooled[idx] = enc(-__builtin_inff());
}

// ---------------- scatters ----------------
__global__ __launch_bounds__(256) void k_scatter_sink(
    float* __restrict__ agg, const float* __restrict__ h,
    const int* __restrict__ sink_nodes, const int* __restrict__ sink_nets,
    const float* __restrict__ ew)
{
    int wv = threadIdx.x >> 6, lane = threadIdx.x & 63;
    int e = blockIdx.x * 4 + wv;
    if (e >= E_SINK) return;
    int sn = sink_nodes[e], tg = sink_nets[e];
    float wt = ew[e];
    atomicAdd(&agg[tg * 64 + lane], h[sn * 64 + lane] * wt);
}

__global__ __launch_bounds__(256) void k_scatter_back_src(
    float* __restrict__ back, const float* __restrict__ g, const int* __restrict__ src_nodes)
{
    int wv = threadIdx.x >> 6, lane = threadIdx.x & 63;
    int n = blockIdx.x * 4 + wv;
    if (n >= N_NETS) return;
    atomicAdd(&back[src_nodes[n] * 64 + lane], g[n * 64 + lane]);
}

__global__ __launch_bounds__(256) void k_scatter_back_sink(
    float* __restrict__ back, const float* __restrict__ g,
    const int* __restrict__ sink_nets, const int* __restrict__ sink_nodes,
    const float* __restrict__ ew)
{
    int wv = threadIdx.x >> 6, lane = threadIdx.x & 63;
    int e = blockIdx.x * 4 + wv;
    if (e >= E_SINK) return;
    int tg = sink_nets[e], dn = sink_nodes[e];
    float wt = ew[e];
    atomicAdd(&back[dn * 64 + lane], g[tg * 64 + lane] * wt);
}

__global__ __launch_bounds__(256) void k_pool_scatter(
    unsigned* __restrict__ pooled, const float* __restrict__ h, const int* __restrict__ batch)
{
    int wv = threadIdx.x >> 6, lane = threadIdx.x & 63;
    int n = blockIdx.x * 4 + wv;
    if (n >= N_NODES) return;
    atomicMax(&pooled[batch[n] * 64 + lane], enc(h[n * 64 + lane]));
}

// ---------------- conv layers (wave per row, in-place) ----------------
__global__ __launch_bounds__(256) void k_conv_net(
    float* __restrict__ g, const float* __restrict__ h, const float* __restrict__ aggsink,
    const int* __restrict__ src_nodes, const float* __restrict__ W, const float* __restrict__ b,
    int apply_leaky_g)
{
    int wv = threadIdx.x >> 6, lane = threadIdx.x & 63;
    int net = blockIdx.x * 4 + wv;
    if (net >= N_NETS) return;
    float gk = g[net * 64 + lane];
    if (apply_leaky_g) gk = leaky(gk);
    int s = src_nodes[net];
    float hs = h[s * 64 + lane];
    float as = aggsink[net * 64 + lane];
    float acc = b[lane];
#pragma unroll 16
    for (int k = 0; k < 64; ++k) acc += __shfl(gk, k, 64) * W[k * 64 + lane];
#pragma unroll 16
    for (int k = 0; k < 64; ++k) acc += __shfl(hs, k, 64) * W[(64 + k) * 64 + lane];
#pragma unroll 16
    for (int k = 0; k < 64; ++k) acc += __shfl(as, k, 64) * W[(128 + k) * 64 + lane];
    g[net * 64 + lane] = acc;   // stored PRE-leaky (back-scatter needs raw g)
}

__global__ __launch_bounds__(256) void k_conv_node(
    float* __restrict__ h, const float* __restrict__ back,
    const float* __restrict__ W, const float* __restrict__ b)
{
    int wv = threadIdx.x >> 6, lane = threadIdx.x & 63;
    int n = blockIdx.x * 4 + wv;
    if (n >= N_NODES) return;
    float hk = h[n * 64 + lane];
    float bk = back[n * 64 + lane];
    float acc = b[lane];
#pragma unroll 16
    for (int k = 0; k < 64; ++k) acc += __shfl(hk, k, 64) * W[k * 64 + lane];
#pragma unroll 16
    for (int k = 0; k < 64; ++k) acc += __shfl(bk, k, 64) * W[(64 + k) * 64 + lane];
    h[n * 64 + lane] = leaky(acc);   // stored POST-leaky
}

// ---------------- virtual-node MLP ----------------
__global__ __launch_bounds__(256) void k_vn_update(
    float* __restrict__ vn, const unsigned* __restrict__ pooled,
    const float* __restrict__ W1, const float* __restrict__ b1,
    const float* __restrict__ W2, const float* __restrict__ b2)
{
    int wv = threadIdx.x >> 6, lane = threadIdx.x & 63;
    int v = blockIdx.x * 4 + wv;
    if (v >= NUM_VN) return;
    float p = dec(pooled[v * 64 + lane]);
    float vv = vn[v * 64 + lane];
    float tmp = p + vv;
    float t1 = b1[lane];
#pragma unroll 16
    for (int k = 0; k < 64; ++k) t1 += __shfl(tmp, k, 64) * W1[k * 64 + lane];
    t1 = leaky(t1);
    float t2 = b2[lane];
#pragma unroll 16
    for (int k = 0; k < 64; ++k) t2 += __shfl(t1, k, 64) * W2[k * 64 + lane];
    vn[v * 64 + lane] = vv + t2;
}

// ---------------- output heads ----------------
__global__ __launch_bounds__(256) void k_fc_node(
    float* __restrict__ out, const float* __restrict__ h,
    const float* __restrict__ W1, const float* __restrict__ b1,
    const float* __restrict__ W2, const float* __restrict__ b2)
{
    int wv = threadIdx.x >> 6, lane = threadIdx.x & 63;
    int n = blockIdx.x * 4 + wv;
    if (n >= N_NODES) return;
    float hk = h[n * 64 + lane];
    float hid[4];
#pragma unroll
    for (int r = 0; r < 4; ++r) {
        float a = b1[lane + 64 * r];
#pragma unroll 16
        for (int k = 0; k < 64; ++k) a += __shfl(hk, k, 64) * W1[k * 256 + lane + 64 * r];
        hid[r] = leaky(a);
    }
    float po[4] = {0.f, 0.f, 0.f, 0.f};
#pragma unroll
    for (int r = 0; r < 4; ++r) {
        int m = lane + 64 * r;
#pragma unroll
        for (int o = 0; o < 4; ++o) po[o] += hid[r] * W2[m * 4 + o];
    }
#pragma unroll
    for (int off = 32; off >= 1; off >>= 1)
#pragma unroll
        for (int o = 0; o < 4; ++o) po[o] += __shfl_xor(po[o], off, 64);
    if (lane < 4) out[n * 4 + lane] = fabsf(po[lane] + b2[lane]);
}

__global__ __launch_bounds__(256) void k_fc_net(
    float* __restrict__ out, const float* __restrict__ g,
    const float* __restrict__ W1, const float* __restrict__ b1,
    const float* __restrict__ W2, const float* __restrict__ b2)
{
    int wv = threadIdx.x >> 6, lane = threadIdx.x & 63;
    int n = blockIdx.x * 4 + wv;
    if (n >= N_NETS) return;
    float gk = leaky(g[n * 64 + lane]);   // stored g is pre-leaky
    float a = b1[lane];
#pragma unroll 16
    for (int k = 0; k < 64; ++k) a += __shfl(gk, k, 64) * W1[k * 64 + lane];
    a = leaky(a);
    float po[4] = {0.f, 0.f, 0.f, 0.f};
#pragma unroll
    for (int o = 0; o < 4; ++o) po[o] += a * W2[lane * 4 + o];
#pragma unroll
    for (int off = 32; off >= 1; off >>= 1)
#pragma unroll
        for (int o = 0; o < 4; ++o) po[o] += __shfl_xor(po[o], off, 64);
    if (lane < 4) out[n * 4 + lane] = fabsf(po[lane] + b2[lane]);
}

extern "C" void kernel_launch(void* const* d_in, const int* in_sizes, int n_in,
                              void* d_out, int out_size, void* d_ws, size_t ws_size,
                              hipStream_t stream)
{
    const float* node_features = (const float*)d_in[0];
    const float* net_features  = (const float*)d_in[1];
    const int*   src_nodes     = (const int*)d_in[2];
    const int*   sink_nodes    = (const int*)d_in[3];
    const int*   sink_nets     = (const int*)d_in[4];
    const float* edge_weight   = (const float*)d_in[5];
    const int*   batch         = (const int*)d_in[6];
    const float* ne_W1 = (const float*)d_in[7];
    const float* ne_b1 = (const float*)d_in[8];
    const float* ne_W2 = (const float*)d_in[9];
    const float* ne_b2 = (const float*)d_in[10];
    const float* te_W1 = (const float*)d_in[11];
    const float* te_b1 = (const float*)d_in[12];
    const float* te_W2 = (const float*)d_in[13];
    const float* te_b2 = (const float*)d_in[14];
    const float* vn_emb = (const float*)d_in[15];
    const float* conv_Wnet  = (const float*)d_in[16];
    const float* conv_bnet  = (const float*)d_in[17];
    const float* conv_Wnode = (const float*)d_in[18];
    const float* conv_bnode = (const float*)d_in[19];
    const float* vn_W1 = (const float*)d_in[20];
    const float* vn_b1 = (const float*)d_in[21];
    const float* vn_W2 = (const float*)d_in[22];
    const float* vn_b2 = (const float*)d_in[23];
    const float* fc1n_W = (const float*)d_in[24];
    const float* fc1n_b = (const float*)d_in[25];
    const float* fc2n_W = (const float*)d_in[26];
    const float* fc2n_b = (const float*)d_in[27];
    const float* fc1e_W = (const float*)d_in[28];
    const float* fc1e_b = (const float*)d_in[29];
    const float* fc2e_W = (const float*)d_in[30];
    const float* fc2e_b = (const float*)d_in[31];

    float* out_node = (float*)d_out;
    float* out_net  = out_node + (size_t)N_NODES * 4;

    // workspace layout (f32)
    float* h       = (float*)d_ws;                       // N_NODES*64
    float* g       = h + (size_t)N_NODES * EMB;          // N_NETS*64
    float* scratch = g + (size_t)N_NETS * EMB;           // N_NODES*64 (aggsink/back)
    float* vn      = scratch + (size_t)N_NODES * EMB;    // NUM_VN*64
    unsigned* pooled = (unsigned*)(vn + (size_t)NUM_VN * EMB);  // NUM_VN*64

    const int nodeBlocks = (N_NODES + 3) / 4;
    const int netBlocks  = (N_NETS + 3) / 4;
    const int edgeBlocks = (E_SINK + 3) / 4;
    const int vnBlocks   = (NUM_VN + 3) / 4;
    const int vnElemBlocks   = (NUM_VN * EMB + 255) / 256;
    const int nodeElemBlocks = (N_NODES * EMB + 255) / 256;

    k_node_enc<<<nodeBlocks, 256, 0, stream>>>(node_features, ne_W1, ne_b1, ne_W2, ne_b2, h);
    k_net_enc<<<netBlocks, 256, 0, stream>>>(net_features, te_W1, te_b1, te_W2, te_b2, g);
    k_vn_init<<<vnElemBlocks, 256, 0, stream>>>(vn, vn_emb);

    for (int l = 0; l < 3; ++l) {
        k_add_vn<<<nodeElemBlocks, 256, 0, stream>>>(h, vn, batch);

        hipMemsetAsync(scratch, 0, (size_t)N_NETS * EMB * sizeof(float), stream);
        k_scatter_sink<<<edgeBlocks, 256, 0, stream>>>(scratch, h, sink_nodes, sink_nets, edge_weight);
        k_conv_net<<<netBlocks, 256, 0, stream>>>(g, h, scratch, src_nodes,
                                                  conv_Wnet + (size_t)l * 192 * 64,
                                                  conv_bnet + (size_t)l * 64, l > 0 ? 1 : 0);

        hipMemsetAsync(scratch, 0, (size_t)N_NODES * EMB * sizeof(float), stream);
        k_scatter_back_src<<<netBlocks, 256, 0, stream>>>(scratch, g, src_nodes);
        k_scatter_back_sink<<<edgeBlocks, 256, 0, stream>>>(scratch, g, sink_nets, sink_nodes, edge_weight);
        k_conv_node<<<nodeBlocks, 256, 0, stream>>>(h, scratch,
                                                    conv_Wnode + (size_t)l * 128 * 64,
                                                    conv_bnode + (size_t)l * 64);

        if (l < 2) {
            k_pool_init<<<vnElemBlocks, 256, 0, stream>>>(pooled);
            k_pool_scatter<<<nodeBlocks, 256, 0, stream>>>(pooled, h, batch);
            k_vn_update<<<vnBlocks, 256, 0, stream>>>(vn, pooled,
                                                      vn_W1 + (size_t)l * 64 * 64,
                                                      vn_b1 + (size_t)l * 64,
                                                      vn_W2 + (size_t)l * 64 * 64,
                                                      vn_b2 + (size_t)l * 64);
        }
    }

    k_fc_node<<<nodeBlocks, 256, 0, stream>>>(out_node, h, fc1n_W, fc1n_b, fc2n_W, fc2n_b);
    k_fc_net<<<netBlocks, 256, 0, stream>>>(out_net, g, fc1e_W, fc1e_b, fc2e_W, fc2e_b);
}

// Round 2
// 3139.053 us; speedup vs baseline: 1.8493x; 1.8493x over previous
//
#include <hip/hip_runtime.h>
#include <cstdint>

static constexpr int N_NODES = 300000;
static constexpr int N_NETS  = 200000;
static constexpr int E_SINK  = 1000000;
static constexpr int NODE_DIM = 32;
static constexpr int NET_DIM  = 16;
static constexpr int EMB = 64;
static constexpr int NUM_VN = 1000;
#define SLOPE 0.01f

__device__ __forceinline__ float leaky(float x) { return x >= 0.f ? x : SLOPE * x; }
__device__ __forceinline__ float4 leaky4(float4 v) {
    return make_float4(leaky(v.x), leaky(v.y), leaky(v.z), leaky(v.w));
}

// order-preserving f32 -> u32 encoding for atomicMax
__device__ __forceinline__ unsigned enc(float x) {
    unsigned u = __float_as_uint(x);
    return (u & 0x80000000u) ? ~u : (u | 0x80000000u);
}
__device__ __forceinline__ float dec(unsigned e) {
    unsigned u = (e & 0x80000000u) ? (e ^ 0x80000000u) : ~e;
    return __uint_as_float(u);
}

// ================= encoders (thread-per-row, W in LDS) =================

// node: 32 -> 128 (leaky) -> 64
__global__ __launch_bounds__(256) void k_node_enc(
    const float* __restrict__ x, const float* __restrict__ W1, const float* __restrict__ b1,
    const float* __restrict__ W2, const float* __restrict__ b2, float* __restrict__ h)
{
    __shared__ float sW1t[128 * 32];  // [m][i] = W1[i][m]
    __shared__ float sW2[128 * 64];   // [m][j]
    __shared__ float sb1[128];
    for (int idx = threadIdx.x; idx < 128 * 32; idx += 256) {
        int i = idx >> 7, m = idx & 127;
        sW1t[m * 32 + i] = W1[idx];
    }
    for (int idx = threadIdx.x; idx < 128 * 64; idx += 256) sW2[idx] = W2[idx];
    if (threadIdx.x < 128) sb1[threadIdx.x] = b1[threadIdx.x];
    __syncthreads();

    int n = blockIdx.x * 256 + threadIdx.x;
    if (n >= N_NODES) return;

    float4 xr[8];
    const float4* xp = (const float4*)(x + (size_t)n * NODE_DIM);
#pragma unroll
    for (int q = 0; q < 8; ++q) xr[q] = xp[q];

    float4 a[16];
    const float4* b2p = (const float4*)b2;
#pragma unroll
    for (int q = 0; q < 16; ++q) a[q] = b2p[q];

    for (int m = 0; m < 128; ++m) {
        const float4* wr = (const float4*)(sW1t + m * 32);
        float p0 = 0.f, p1 = 0.f, p2 = 0.f, p3 = 0.f;
#pragma unroll
        for (int q = 0; q < 8; ++q) {
            float4 v = wr[q];
            p0 += xr[q].x * v.x; p1 += xr[q].y * v.y;
            p2 += xr[q].z * v.z; p3 += xr[q].w * v.w;
        }
        float hm = leaky(sb1[m] + ((p0 + p1) + (p2 + p3)));
        const float4* w2r = (const float4*)(sW2 + m * 64);
#pragma unroll
        for (int q = 0; q < 16; ++q) {
            float4 v = w2r[q];
            a[q].x += hm * v.x; a[q].y += hm * v.y;
            a[q].z += hm * v.z; a[q].w += hm * v.w;
        }
    }
    float4* hp = (float4*)(h + (size_t)n * EMB);
#pragma unroll
    for (int q = 0; q < 16; ++q) hp[q] = a[q];
}

// net: 16 -> 64 (leaky) -> 64
__global__ __launch_bounds__(256) void k_net_enc(
    const float* __restrict__ x, const float* __restrict__ W1, const float* __restrict__ b1,
    const float* __restrict__ W2, const float* __restrict__ b2, float* __restrict__ g)
{
    __shared__ float sW1t[64 * 16];   // [m][i]
    __shared__ float sW2[64 * 64];
    __shared__ float sb1[64];
    for (int idx = threadIdx.x; idx < 64 * 16; idx += 256) {
        int i = idx >> 6, m = idx & 63;
        sW1t[m * 16 + i] = W1[idx];
    }
    for (int idx = threadIdx.x; idx < 64 * 64; idx += 256) sW2[idx] = W2[idx];
    if (threadIdx.x < 64) sb1[threadIdx.x] = b1[threadIdx.x];
    __syncthreads();

    int n = blockIdx.x * 256 + threadIdx.x;
    if (n >= N_NETS) return;

    float4 xr[4];
    const float4* xp = (const float4*)(x + (size_t)n * NET_DIM);
#pragma unroll
    for (int q = 0; q < 4; ++q) xr[q] = xp[q];

    float4 a[16];
    const float4* b2p = (const float4*)b2;
#pragma unroll
    for (int q = 0; q < 16; ++q) a[q] = b2p[q];

    for (int m = 0; m < 64; ++m) {
        const float4* wr = (const float4*)(sW1t + m * 16);
        float p0 = 0.f, p1 = 0.f, p2 = 0.f, p3 = 0.f;
#pragma unroll
        for (int q = 0; q < 4; ++q) {
            float4 v = wr[q];
            p0 += xr[q].x * v.x; p1 += xr[q].y * v.y;
            p2 += xr[q].z * v.z; p3 += xr[q].w * v.w;
        }
        float hm = leaky(sb1[m] + ((p0 + p1) + (p2 + p3)));
        const float4* w2r = (const float4*)(sW2 + m * 64);
#pragma unroll
        for (int q = 0; q < 16; ++q) {
            float4 v = w2r[q];
            a[q].x += hm * v.x; a[q].y += hm * v.y;
            a[q].z += hm * v.z; a[q].w += hm * v.w;
        }
    }
    float4* gp = (float4*)(g + (size_t)n * EMB);
#pragma unroll
    for (int q = 0; q < 16; ++q) gp[q] = a[q];
}

// ================= misc elementwise =================
__global__ void k_vn_init(float* __restrict__ vn, const float* __restrict__ vn_emb) {
    int idx = blockIdx.x * blockDim.x + threadIdx.x;
    if (idx < NUM_VN * EMB) vn[idx] = vn_emb[idx & 63];
}

__global__ void k_add_vn(float* __restrict__ h, const float* __restrict__ vn,
                         const int* __restrict__ batch) {
    int idx = blockIdx.x * blockDim.x + threadIdx.x;
    if (idx >= N_NODES * EMB) return;
    int n = idx >> 6, c = idx & 63;
    h[idx] += vn[batch[n] * 64 + c];
}

__global__ void k_pool_init(unsigned* __restrict__ pooled) {
    int idx = blockIdx.x * blockDim.x + threadIdx.x;
    if (idx < NUM_VN * EMB) pooled[idx] = enc(-__builtin_inff());
}

// ================= scatters (wave per edge/row) =================
__global__ __launch_bounds__(256) void k_scatter_sink(
    float* __restrict__ agg, const float* __restrict__ h,
    const int* __restrict__ sink_nodes, const int* __restrict__ sink_nets,
    const float* __restrict__ ew)
{
    int wv = threadIdx.x >> 6, lane = threadIdx.x & 63;
    int e = blockIdx.x * 4 + wv;
    if (e >= E_SINK) return;
    int sn = sink_nodes[e], tg = sink_nets[e];
    float wt = ew[e];
    atomicAdd(&agg[(size_t)tg * 64 + lane], h[(size_t)sn * 64 + lane] * wt);
}

__global__ __launch_bounds__(256) void k_scatter_back_src(
    float* __restrict__ back, const float* __restrict__ g, const int* __restrict__ src_nodes)
{
    int wv = threadIdx.x >> 6, lane = threadIdx.x & 63;
    int n = blockIdx.x * 4 + wv;
    if (n >= N_NETS) return;
    atomicAdd(&back[(size_t)src_nodes[n] * 64 + lane], g[(size_t)n * 64 + lane]);
}

__global__ __launch_bounds__(256) void k_scatter_back_sink(
    float* __restrict__ back, const float* __restrict__ g,
    const int* __restrict__ sink_nets, const int* __restrict__ sink_nodes,
    const float* __restrict__ ew)
{
    int wv = threadIdx.x >> 6, lane = threadIdx.x & 63;
    int e = blockIdx.x * 4 + wv;
    if (e >= E_SINK) return;
    int tg = sink_nets[e], dn = sink_nodes[e];
    float wt = ew[e];
    atomicAdd(&back[(size_t)dn * 64 + lane], g[(size_t)tg * 64 + lane] * wt);
}

__global__ __launch_bounds__(256) void k_pool_scatter(
    unsigned* __restrict__ pooled, const float* __restrict__ h, const int* __restrict__ batch)
{
    int wv = threadIdx.x >> 6, lane = threadIdx.x & 63;
    int n = blockIdx.x * 4 + wv;
    if (n >= N_NODES) return;
    atomicMax(&pooled[batch[n] * 64 + lane], enc(h[(size_t)n * 64 + lane]));
}

// ================= conv layers (thread-per-row, W in LDS) =================

// g_new = cat(g|leaky, h[src], aggsink) @ W(192x64) + b   (stored PRE-leaky)
__global__ __launch_bounds__(256) void k_conv_net(
    float* __restrict__ g, const float* __restrict__ h, const float* __restrict__ aggsink,
    const int* __restrict__ src_nodes, const float* __restrict__ W, const float* __restrict__ b,
    int apply_leaky_g)
{
    __shared__ float sW[192 * 64];    // 48 KB, row-major [k][j]
    __shared__ float sb[64];
    for (int idx = threadIdx.x; idx < 192 * 64; idx += 256) sW[idx] = W[idx];
    if (threadIdx.x < 64) sb[threadIdx.x] = b[threadIdx.x];
    __syncthreads();

    int n = blockIdx.x * 256 + threadIdx.x;
    if (n >= N_NETS) return;

    float4 a[16];
#pragma unroll
    for (int q = 0; q < 16; ++q) {
        const float4* bp = (const float4*)sb;
        a[q] = bp[q];
    }

    const float4* rows[3];
    rows[0] = (const float4*)(g + (size_t)n * 64);
    rows[1] = (const float4*)(h + (size_t)src_nodes[n] * 64);
    rows[2] = (const float4*)(aggsink + (size_t)n * 64);

    for (int part = 0; part < 3; ++part) {
        const float4* rp = rows[part];
        const float* wbase = sW + part * 64 * 64;
        bool lk = (part == 0) && apply_leaky_g;
        for (int k4 = 0; k4 < 16; ++k4) {
            float4 iv = rp[k4];
            if (lk) iv = leaky4(iv);
            const float4* w0 = (const float4*)(wbase + (k4 * 4 + 0) * 64);
            const float4* w1 = (const float4*)(wbase + (k4 * 4 + 1) * 64);
            const float4* w2 = (const float4*)(wbase + (k4 * 4 + 2) * 64);
            const float4* w3 = (const float4*)(wbase + (k4 * 4 + 3) * 64);
#pragma unroll
            for (int q = 0; q < 16; ++q) {
                float4 v0 = w0[q], v1 = w1[q], v2 = w2[q], v3 = w3[q];
                a[q].x += iv.x * v0.x + iv.y * v1.x + iv.z * v2.x + iv.w * v3.x;
                a[q].y += iv.x * v0.y + iv.y * v1.y + iv.z * v2.y + iv.w * v3.y;
                a[q].z += iv.x * v0.z + iv.y * v1.z + iv.z * v2.z + iv.w * v3.z;
                a[q].w += iv.x * v0.w + iv.y * v1.w + iv.z * v2.w + iv.w * v3.w;
            }
        }
    }
    float4* gp = (float4*)(g + (size_t)n * 64);
#pragma unroll
    for (int q = 0; q < 16; ++q) gp[q] = a[q];
}

// h_new = leaky( cat(h, back) @ W(128x64) + b )
__global__ __launch_bounds__(256) void k_conv_node(
    float* __restrict__ h, const float* __restrict__ back,
    const float* __restrict__ W, const float* __restrict__ b)
{
    __shared__ float sW[128 * 64];    // 32 KB
    __shared__ float sb[64];
    for (int idx = threadIdx.x; idx < 128 * 64; idx += 256) sW[idx] = W[idx];
    if (threadIdx.x < 64) sb[threadIdx.x] = b[threadIdx.x];
    __syncthreads();

    int n = blockIdx.x * 256 + threadIdx.x;
    if (n >= N_NODES) return;

    float4 a[16];
#pragma unroll
    for (int q = 0; q < 16; ++q) {
        const float4* bp = (const float4*)sb;
        a[q] = bp[q];
    }

    const float4* rows[2];
    rows[0] = (const float4*)(h + (size_t)n * 64);
    rows[1] = (const float4*)(back + (size_t)n * 64);

    for (int part = 0; part < 2; ++part) {
        const float4* rp = rows[part];
        const float* wbase = sW + part * 64 * 64;
        for (int k4 = 0; k4 < 16; ++k4) {
            float4 iv = rp[k4];
            const float4* w0 = (const float4*)(wbase + (k4 * 4 + 0) * 64);
            const float4* w1 = (const float4*)(wbase + (k4 * 4 + 1) * 64);
            const float4* w2 = (const float4*)(wbase + (k4 * 4 + 2) * 64);
            const float4* w3 = (const float4*)(wbase + (k4 * 4 + 3) * 64);
#pragma unroll
            for (int q = 0; q < 16; ++q) {
                float4 v0 = w0[q], v1 = w1[q], v2 = w2[q], v3 = w3[q];
                a[q].x += iv.x * v0.x + iv.y * v1.x + iv.z * v2.x + iv.w * v3.x;
                a[q].y += iv.x * v0.y + iv.y * v1.y + iv.z * v2.y + iv.w * v3.y;
                a[q].z += iv.x * v0.z + iv.y * v1.z + iv.z * v2.z + iv.w * v3.z;
                a[q].w += iv.x * v0.w + iv.y * v1.w + iv.z * v2.w + iv.w * v3.w;
            }
        }
    }
    float4* hp = (float4*)(h + (size_t)n * 64);
#pragma unroll
    for (int q = 0; q < 16; ++q) hp[q] = leaky4(a[q]);
}

// ================= virtual-node MLP (tiny: 1000 rows) =================
__global__ __launch_bounds__(256) void k_vn_update(
    float* __restrict__ vn, const unsigned* __restrict__ pooled,
    const float* __restrict__ W1, const float* __restrict__ b1,
    const float* __restrict__ W2, const float* __restrict__ b2)
{
    int wv = threadIdx.x >> 6, lane = threadIdx.x & 63;
    int v = blockIdx.x * 4 + wv;
    if (v >= NUM_VN) return;
    float p = dec(pooled[v * 64 + lane]);
    float vv = vn[v * 64 + lane];
    float tmp = p + vv;
    float t1 = b1[lane];
#pragma unroll 16
    for (int k = 0; k < 64; ++k) t1 += __shfl(tmp, k, 64) * W1[k * 64 + lane];
    t1 = leaky(t1);
    float t2 = b2[lane];
#pragma unroll 16
    for (int k = 0; k < 64; ++k) t2 += __shfl(t1, k, 64) * W2[k * 64 + lane];
    vn[v * 64 + lane] = vv + t2;
}

// ================= output heads (thread-per-row) =================

// node: 64 -> 256 (leaky) -> 4, abs
__global__ __launch_bounds__(256) void k_fc_node(
    float* __restrict__ out, const float* __restrict__ h,
    const float* __restrict__ W1, const float* __restrict__ b1,
    const float* __restrict__ W2, const float* __restrict__ b2)
{
    __shared__ float sW1t[256 * 64];  // 64 KB, [r][k] = W1[k][r]
    __shared__ float sW2[256 * 4];    // [r][o]
    __shared__ float sb1[256];
    for (int idx = threadIdx.x; idx < 256 * 64; idx += 256) {
        int k = idx >> 8, r = idx & 255;
        sW1t[r * 64 + k] = W1[idx];
    }
    for (int idx = threadIdx.x; idx < 256 * 4; idx += 256) sW2[idx] = W2[idx];
    sb1[threadIdx.x] = b1[threadIdx.x];
    __syncthreads();

    int n = blockIdx.x * 256 + threadIdx.x;
    if (n >= N_NODES) return;

    float4 hr[16];
    const float4* hp = (const float4*)(h + (size_t)n * 64);
#pragma unroll
    for (int q = 0; q < 16; ++q) hr[q] = hp[q];

    float po0 = 0.f, po1 = 0.f, po2 = 0.f, po3 = 0.f;
    for (int r = 0; r < 256; ++r) {
        const float4* wr = (const float4*)(sW1t + r * 64);
        float p0 = 0.f, p1 = 0.f, p2 = 0.f, p3 = 0.f;
#pragma unroll
        for (int q = 0; q < 16; ++q) {
            float4 v = wr[q];
            p0 += hr[q].x * v.x; p1 += hr[q].y * v.y;
            p2 += hr[q].z * v.z; p3 += hr[q].w * v.w;
        }
        float act = leaky(sb1[r] + ((p0 + p1) + (p2 + p3)));
        const float4* w2 = (const float4*)(sW2 + r * 4);
        float4 v2 = w2[0];
        po0 += act * v2.x; po1 += act * v2.y; po2 += act * v2.z; po3 += act * v2.w;
    }
    float4 ov = make_float4(fabsf(po0 + b2[0]), fabsf(po1 + b2[1]),
                            fabsf(po2 + b2[2]), fabsf(po3 + b2[3]));
    *((float4*)(out + (size_t)n * 4)) = ov;
}

// net: 64 -> 64 (leaky) -> 4, abs   (input g stored pre-leaky)
__global__ __launch_bounds__(256) void k_fc_net(
    float* __restrict__ out, const float* __restrict__ g,
    const float* __restrict__ W1, const float* __restrict__ b1,
    const float* __restrict__ W2, const float* __restrict__ b2)
{
    __shared__ float sW1t[64 * 64];   // 16 KB, [r][k]
    __shared__ float sW2[64 * 4];
    __shared__ float sb1[64];
    for (int idx = threadIdx.x; idx < 64 * 64; idx += 256) {
        int k = idx >> 6, r = idx & 63;
        sW1t[r * 64 + k] = W1[idx];
    }
    for (int idx = threadIdx.x; idx < 64 * 4; idx += 256) sW2[idx] = W2[idx];
    if (threadIdx.x < 64) sb1[threadIdx.x] = b1[threadIdx.x];
    __syncthreads();

    int n = blockIdx.x * 256 + threadIdx.x;
    if (n >= N_NETS) return;

    float4 gr[16];
    const float4* gp = (const float4*)(g + (size_t)n * 64);
#pragma unroll
    for (int q = 0; q < 16; ++q) gr[q] = leaky4(gp[q]);

    float po0 = 0.f, po1 = 0.f, po2 = 0.f, po3 = 0.f;
    for (int r = 0; r < 64; ++r) {
        const float4* wr = (const float4*)(sW1t + r * 64);
        float p0 = 0.f, p1 = 0.f, p2 = 0.f, p3 = 0.f;
#pragma unroll
        for (int q = 0; q < 16; ++q) {
            float4 v = wr[q];
            p0 += gr[q].x * v.x; p1 += gr[q].y * v.y;
            p2 += gr[q].z * v.z; p3 += gr[q].w * v.w;
        }
        float act = leaky(sb1[r] + ((p0 + p1) + (p2 + p3)));
        const float4* w2 = (const float4*)(sW2 + r * 4);
        float4 v2 = w2[0];
        po0 += act * v2.x; po1 += act * v2.y; po2 += act * v2.z; po3 += act * v2.w;
    }
    float4 ov = make_float4(fabsf(po0 + b2[0]), fabsf(po1 + b2[1]),
                            fabsf(po2 + b2[2]), fabsf(po3 + b2[3]));
    *((float4*)(out + (size_t)n * 4)) = ov;
}

extern "C" void kernel_launch(void* const* d_in, const int* in_sizes, int n_in,
                              void* d_out, int out_size, void* d_ws, size_t ws_size,
                              hipStream_t stream)
{
    const float* node_features = (const float*)d_in[0];
    const float* net_features  = (const float*)d_in[1];
    const int*   src_nodes     = (const int*)d_in[2];
    const int*   sink_nodes    = (const int*)d_in[3];
    const int*   sink_nets     = (const int*)d_in[4];
    const float* edge_weight   = (const float*)d_in[5];
    const int*   batch         = (const int*)d_in[6];
    const float* ne_W1 = (const float*)d_in[7];
    const float* ne_b1 = (const float*)d_in[8];
    const float* ne_W2 = (const float*)d_in[9];
    const float* ne_b2 = (const float*)d_in[10];
    const float* te_W1 = (const float*)d_in[11];
    const float* te_b1 = (const float*)d_in[12];
    const float* te_W2 = (const float*)d_in[13];
    const float* te_b2 = (const float*)d_in[14];
    const float* vn_emb = (const float*)d_in[15];
    const float* conv_Wnet  = (const float*)d_in[16];
    const float* conv_bnet  = (const float*)d_in[17];
    const float* conv_Wnode = (const float*)d_in[18];
    const float* conv_bnode = (const float*)d_in[19];
    const float* vn_W1 = (const float*)d_in[20];
    const float* vn_b1 = (const float*)d_in[21];
    const float* vn_W2 = (const float*)d_in[22];
    const float* vn_b2 = (const float*)d_in[23];
    const float* fc1n_W = (const float*)d_in[24];
    const float* fc1n_b = (const float*)d_in[25];
    const float* fc2n_W = (const float*)d_in[26];
    const float* fc2n_b = (const float*)d_in[27];
    const float* fc1e_W = (const float*)d_in[28];
    const float* fc1e_b = (const float*)d_in[29];
    const float* fc2e_W = (const float*)d_in[30];
    const float* fc2e_b = (const float*)d_in[31];

    float* out_node = (float*)d_out;
    float* out_net  = out_node + (size_t)N_NODES * 4;

    float* h       = (float*)d_ws;                       // N_NODES*64
    float* g       = h + (size_t)N_NODES * EMB;          // N_NETS*64
    float* scratch = g + (size_t)N_NETS * EMB;           // N_NODES*64 (aggsink/back)
    float* vn      = scratch + (size_t)N_NODES * EMB;    // NUM_VN*64
    unsigned* pooled = (unsigned*)(vn + (size_t)NUM_VN * EMB);  // NUM_VN*64

    const int nodeRowBlocks = (N_NODES + 255) / 256;
    const int netRowBlocks  = (N_NETS + 255) / 256;
    const int nodeWaveBlocks = (N_NODES + 3) / 4;
    const int netWaveBlocks  = (N_NETS + 3) / 4;
    const int edgeBlocks = (E_SINK + 3) / 4;
    const int vnBlocks   = (NUM_VN + 3) / 4;
    const int vnElemBlocks   = (NUM_VN * EMB + 255) / 256;
    const int nodeElemBlocks = (N_NODES * EMB + 255) / 256;

    k_node_enc<<<nodeRowBlocks, 256, 0, stream>>>(node_features, ne_W1, ne_b1, ne_W2, ne_b2, h);
    k_net_enc<<<netRowBlocks, 256, 0, stream>>>(net_features, te_W1, te_b1, te_W2, te_b2, g);
    k_vn_init<<<vnElemBlocks, 256, 0, stream>>>(vn, vn_emb);

    for (int l = 0; l < 3; ++l) {
        k_add_vn<<<nodeElemBlocks, 256, 0, stream>>>(h, vn, batch);

        hipMemsetAsync(scratch, 0, (size_t)N_NETS * EMB * sizeof(float), stream);
        k_scatter_sink<<<edgeBlocks, 256, 0, stream>>>(scratch, h, sink_nodes, sink_nets, edge_weight);
        k_conv_net<<<netRowBlocks, 256, 0, stream>>>(g, h, scratch, src_nodes,
                                                     conv_Wnet + (size_t)l * 192 * 64,
                                                     conv_bnet + (size_t)l * 64, l > 0 ? 1 : 0);

        hipMemsetAsync(scratch, 0, (size_t)N_NODES * EMB * sizeof(float), stream);
        k_scatter_back_src<<<netWaveBlocks, 256, 0, stream>>>(scratch, g, src_nodes);
        k_scatter_back_sink<<<edgeBlocks, 256, 0, stream>>>(scratch, g, sink_nets, sink_nodes, edge_weight);
        k_conv_node<<<nodeRowBlocks, 256, 0, stream>>>(h, scratch,
                                                       conv_Wnode + (size_t)l * 128 * 64,
                                                       conv_bnode + (size_t)l * 64);

        if (l < 2) {
            k_pool_init<<<vnElemBlocks, 256, 0, stream>>>(pooled);
            k_pool_scatter<<<nodeWaveBlocks, 256, 0, stream>>>(pooled, h, batch);
            k_vn_update<<<vnBlocks, 256, 0, stream>>>(vn, pooled,
                                                      vn_W1 + (size_t)l * 64 * 64,
                                                      vn_b1 + (size_t)l * 64,
                                                      vn_W2 + (size_t)l * 64 * 64,
                                                      vn_b2 + (size_t)l * 64);
        }
    }

    k_fc_node<<<nodeRowBlocks, 256, 0, stream>>>(out_node, h, fc1n_W, fc1n_b, fc2n_W, fc2n_b);
    k_fc_net<<<netRowBlocks, 256, 0, stream>>>(out_net, g, fc1e_W, fc1e_b, fc2e_W, fc2e_b);
}